// Round 17
// baseline (109.509 us; speedup 1.0000x reference)
//
#include <hip/hip_runtime.h>
#include <hip/hip_bf16.h>
#include <math.h>

typedef __hip_bfloat16 bf16;
typedef __attribute__((ext_vector_type(8))) short short8;
typedef __attribute__((ext_vector_type(4))) float floatx4;

static constexpr int Bn = 2, Sn = 2048, Hn = 16, DHn = 64, DIMn = 1024;
static constexpr int Mn = Bn * Sn;  // 4096 tokens

#if __has_builtin(__builtin_amdgcn_exp2f)
#define EXP2(x) __builtin_amdgcn_exp2f(x)
#else
#define EXP2(x) exp2f(x)
#endif

__device__ __forceinline__ unsigned short bfbits(float f) {
  union { __hip_bfloat16 h; unsigned short u; } cv;
  cv.h = __float2bfloat16(f);
  return cv.u;
}

__device__ __forceinline__ float bf2f(unsigned short u) {
  union { float f; unsigned int u; } cv;
  cv.u = ((unsigned int)u) << 16;
  return cv.f;
}

__device__ __forceinline__ unsigned int fbu(float f) {
  union { float f; unsigned int u; } cv;
  cv.f = f;
  return cv.u;
}

// one-instruction truncate-pack: result = (bf16(hi)<<16) | bf16(lo)
__device__ __forceinline__ unsigned int pack_bf16(float lo, float hi) {
  return __builtin_amdgcn_perm(fbu(hi), fbu(lo), 0x07060302u);
}

// async global->LDS, 16B per lane. dst is wave-uniform base; HW adds lane*16.
__device__ __forceinline__ void gload_lds16(const void* g, void* l) {
  __builtin_amdgcn_global_load_lds(
      (const __attribute__((address_space(1))) uint32_t*)g,
      (__attribute__((address_space(3))) uint32_t*)l, 16, 0, 0);
}

// counted waits (T4). sched_barrier pins per rule #18.
template <int N>
__device__ __forceinline__ void wait_vm() {
  if constexpr (N == 0) asm volatile("s_waitcnt vmcnt(0)" ::: "memory");
  else if constexpr (N == 2) asm volatile("s_waitcnt vmcnt(2)" ::: "memory");
  else if constexpr (N == 3) asm volatile("s_waitcnt vmcnt(3)" ::: "memory");
  else if constexpr (N == 4) asm volatile("s_waitcnt vmcnt(4)" ::: "memory");
  else asm volatile("s_waitcnt vmcnt(6)" ::: "memory");
  __builtin_amdgcn_sched_barrier(0);
}

// ---------------- fused prep: x->bf16 | 4 weights->bf16 | rope tables ----------------
__global__ void prep_kernel(const float* __restrict__ x,
                            const float* __restrict__ a0, const float* __restrict__ a1,
                            const float* __restrict__ a2, const float* __restrict__ a3,
                            unsigned short* __restrict__ xo,
                            unsigned short* __restrict__ o0, unsigned short* __restrict__ o1,
                            unsigned short* __restrict__ o2, unsigned short* __restrict__ o3,
                            float* __restrict__ tc, float* __restrict__ ts) {
  const int bid = blockIdx.x;
  if (bid < 8192) {
    const float* s;
    unsigned short* d;
    int i;
    if (bid < 4096) {
      s = x; d = xo; i = bid * 256 + threadIdx.x;
    } else {
      int wsel = (bid - 4096) >> 10;
      s = (wsel == 0) ? a0 : (wsel == 1) ? a1 : (wsel == 2) ? a2 : a3;
      d = (wsel == 0) ? o0 : (wsel == 1) ? o1 : (wsel == 2) ? o2 : o3;
      i = ((bid - 4096) & 1023) * 256 + threadIdx.x;
    }
    float4 v = ((const float4*)s)[i];
    ushort4 o;
    o.x = bfbits(v.x); o.y = bfbits(v.y); o.z = bfbits(v.z); o.w = bfbits(v.w);
    ((ushort4*)d)[i] = o;
  } else {
    int t = (bid - 8192) * 256 + threadIdx.x;  // 2048*32 = 65536
    int pos = t >> 5, i = t & 31;
    float f = powf(10000.0f, -(float)i * (1.0f / 32.0f));
    float a = (float)pos * f;
    tc[t] = cosf(a);
    ts[t] = sinf(a);
  }
}

// ---------------- fused QKV GEMM + RoPE + l2norm: 128m x 128n (2 heads) ----------------
// BK=64, 128B LDS rows, XOR-swizzled. A double-buffered, B single-buffered.
// Q rows additionally pre-scaled by exp(logit_scale)*0.125*log2e (folds the
// softmax scale into the bf16 Q operand — attn consumes scores scale-free).
__global__ __launch_bounds__(256, 3) void qkv_kernel(
    const bf16* __restrict__ A,
    const bf16* __restrict__ Wq, const bf16* __restrict__ Wk, const bf16* __restrict__ Wv,
    const float* __restrict__ bq, const float* __restrict__ bk, const float* __restrict__ bv,
    const float* __restrict__ tc, const float* __restrict__ ts,
    const float* __restrict__ ls,
    unsigned short* __restrict__ qo, unsigned short* __restrict__ ko,
    unsigned short* __restrict__ vt) {
  __shared__ bf16 smem[24576];  // sA[2][8192] 32KB | sB[8192] 16KB; ct reuses sA
  bf16* sAp = smem;
  bf16* sBp = smem + 16384;
  const int sel = blockIdx.y >> 3;
  const bf16* Bw = (sel == 0) ? Wq : (sel == 1) ? Wk : Wv;
  const float* bias = (sel == 0) ? bq : (sel == 1) ? bk : bv;
  const int tid = threadIdx.x;
  const int lane = tid & 63, wave = tid >> 6;
  const int fr = lane & 15, fq = lane >> 4;
  const int m0 = blockIdx.x * 128, n0 = (blockIdx.y & 7) * 128;

  floatx4 acc[2][8] = {};  // [mi][ni]

  auto stageA = [&](int buf, int k0) {
#pragma unroll
    for (int call = 0; call < 4; ++call) {
      int row = call * 32 + (tid >> 3);
      int sb = ((tid & 7) * 16) ^ ((row & 7) << 4);
      gload_lds16(A + (size_t)(m0 + row) * 1024 + k0 + sb / 2,
                  sAp + buf * 8192 + call * 2048 + wave * 512);
    }
  };
  auto stageB = [&](int k0) {
#pragma unroll
    for (int call = 0; call < 4; ++call) {
      int row = call * 32 + (tid >> 3);
      int sb = ((tid & 7) * 16) ^ ((row & 7) << 4);
      gload_lds16(Bw + (size_t)(n0 + row) * 1024 + k0 + sb / 2,
                  sBp + call * 2048 + wave * 512);
    }
  };

  stageB(0);
  stageA(0, 0);
  stageA(1, 64);
  int cur = 0;
  for (int k0 = 0; k0 < 1024; k0 += 64) {
    if (k0 + 64 < 1024) wait_vm<4>(); else wait_vm<0>();
    __builtin_amdgcn_s_barrier();
    __builtin_amdgcn_sched_barrier(0);
    const char* sAc = (const char*)(sAp + cur * 8192);
    const char* sBc = (const char*)sBp;
    short8 af[2][2];
#pragma unroll
    for (int mi = 0; mi < 2; ++mi) {
      int arow = wave * 32 + mi * 16 + fr;
      int asw = (arow & 7) << 4;
#pragma unroll
      for (int kc = 0; kc < 2; ++kc)
        af[mi][kc] = *(const short8*)(sAc + arow * 128 + ((kc * 64 + fq * 16) ^ asw));
    }
#pragma unroll
    for (int nh = 0; nh < 2; ++nh) {
      short8 bfr[4][2];
#pragma unroll
      for (int n4 = 0; n4 < 4; ++n4) {
        int brow = (nh * 4 + n4) * 16 + fr;
        int bsw = (brow & 7) << 4;
#pragma unroll
        for (int kc = 0; kc < 2; ++kc)
          bfr[n4][kc] = *(const short8*)(sBc + brow * 128 + ((kc * 64 + fq * 16) ^ bsw));
      }
#pragma unroll
      for (int mi = 0; mi < 2; ++mi)
#pragma unroll
        for (int n4 = 0; n4 < 4; ++n4)
#pragma unroll
          for (int kc = 0; kc < 2; ++kc)
            acc[mi][nh * 4 + n4] = __builtin_amdgcn_mfma_f32_16x16x32_bf16(
                af[mi][kc], bfr[n4][kc], acc[mi][nh * 4 + n4], 0, 0, 0);
    }
    __builtin_amdgcn_sched_barrier(0);
    __builtin_amdgcn_s_barrier();
    if (k0 + 64 < 1024) stageB(k0 + 64);
    if (k0 + 128 < 1024) stageA(cur, k0 + 128);
    cur ^= 1;
  }

  if (sel < 2) {
    // fused bias + RoPE + l2norm epilogue (f32) per head; write [B,H,S,64]
    // Q only: fold softmax scale into the stored operand.
    unsigned short* dst = (sel == 0) ? qo : ko;
    const float qscale = (sel == 0) ? (__expf(ls[0]) * 0.125f * 1.44269504f) : 1.0f;
    const int h0 = n0 >> 6;
    float bias_d[8];
#pragma unroll
    for (int ni = 0; ni < 8; ++ni) bias_d[ni] = bias[n0 + ni * 16 + fr];
#pragma unroll
    for (int mi = 0; mi < 2; ++mi)
#pragma unroll
      for (int j = 0; j < 4; ++j) {
        int m = m0 + wave * 32 + mi * 16 + fq * 4 + j;
        int b = m >> 11, srow = m & 2047;
#pragma unroll
        for (int hh = 0; hh < 2; ++hh) {
          float y[4], ss = 0.f;
#pragma unroll
          for (int n4 = 0; n4 < 4; ++n4) {
            int ni = hh * 4 + n4;
            float val = acc[mi][ni][j] + bias_d[ni];
            float prt = __shfl_xor(val, 1);
            int d = n4 * 16 + fr;  // dim within head
            int jj = d >> 1;
            float cc = tc[srow * 32 + jj], sn = ts[srow * 32 + jj];
            y[n4] = (d & 1) ? (val * cc + prt * sn) : (val * cc - prt * sn);
            ss += y[n4] * y[n4];
          }
          ss += __shfl_xor(ss, 1);
          ss += __shfl_xor(ss, 2);
          ss += __shfl_xor(ss, 4);
          ss += __shfl_xor(ss, 8);
          float inv = rsqrtf(ss + 1e-6f) * qscale;
          size_t ob = ((size_t)(b * 16 + h0 + hh) * 2048 + srow) * 64;
#pragma unroll
          for (int n4 = 0; n4 < 4; ++n4)
            dst[ob + n4 * 16 + fr] = bfbits(y[n4] * inv);
        }
      }
  } else {
    // V: transpose through LDS (256B rows), kv-permuted store per 64-group.
    __syncthreads();
    char* ct = (char*)smem;  // [nl 128][ml 128] bf16, 256B rows, ^=(nl&15)<<4
#pragma unroll
    for (int mi = 0; mi < 2; ++mi)
#pragma unroll
      for (int ni = 0; ni < 8; ++ni) {
        int nl = ni * 16 + fr;
        float bi = bias[n0 + nl];
#pragma unroll
        for (int j = 0; j < 4; j += 2) {
          int ml = wave * 32 + mi * 16 + fq * 4 + j;
          unsigned int u = pack_bf16(acc[mi][ni][j] + bi, acc[mi][ni][j + 1] + bi);
          *(unsigned int*)(ct + nl * 256 + ((ml * 2) ^ ((nl & 15) << 4))) = u;
        }
      }
    __syncthreads();
    int nl2 = tid >> 1, half = tid & 1;
    int head = (n0 >> 6) + (nl2 >> 6), dd = nl2 & 63;
    int b = m0 >> 11, s0 = m0 & 2047;
    unsigned short* orow =
        vt + (((size_t)b * 16 + head) * 64 + dd) * 2048 + s0 + half * 64;
    int swz = (nl2 & 15) << 4;
    const char* rowp = ct + nl2 * 256;
#pragma unroll
    for (int ch = 0; ch < 4; ++ch) {
      int cb = half * 128 + 32 * (ch >> 1) + 16 * (ch & 1);
      union { long long l[2]; short8 v; } s1, s2;
      s1.l[0] = *(const long long*)(rowp + ((cb) ^ swz));
      s1.l[1] = *(const long long*)(rowp + ((cb + 64) ^ swz));
      s2.l[0] = *(const long long*)(rowp + ((cb + 8) ^ swz));
      s2.l[1] = *(const long long*)(rowp + ((cb + 72) ^ swz));
      *(short8*)(orow + ch * 16) = s1.v;
      *(short8*)(orow + ch * 16 + 8) = s2.v;
    }
  }
}

// ---------------- Wo GEMM: 128m x 64n tiles, BK=64, swizzled, f32 out ----------------
__global__ __launch_bounds__(256, 3) void gemm_bt_kernel(
    const bf16* __restrict__ A, const bf16* __restrict__ Bw,
    const float* __restrict__ bias, float* __restrict__ Cf) {
  __shared__ bf16 smem[24576];  // sA[2][8192] | sB[2][4096]
  bf16* sAp = smem;
  bf16* sBp = smem + 16384;
  const int tid = threadIdx.x;
  const int lane = tid & 63, wave = tid >> 6;
  const int fr = lane & 15, fq = lane >> 4;
  const int m0 = blockIdx.x * 128, n0 = blockIdx.y * 64;

  floatx4 acc[2][4] = {};

  auto stage = [&](int buf, int k0) {
#pragma unroll
    for (int call = 0; call < 4; ++call) {
      int row = call * 32 + (tid >> 3);
      int sb = ((tid & 7) * 16) ^ ((row & 7) << 4);
      gload_lds16(A + (size_t)(m0 + row) * 1024 + k0 + sb / 2,
                  sAp + buf * 8192 + call * 2048 + wave * 512);
    }
#pragma unroll
    for (int call = 0; call < 2; ++call) {
      int row = call * 32 + (tid >> 3);
      int sb = ((tid & 7) * 16) ^ ((row & 7) << 4);
      gload_lds16(Bw + (size_t)(n0 + row) * 1024 + k0 + sb / 2,
                  sBp + buf * 4096 + call * 2048 + wave * 512);
    }
  };

  stage(0, 0);
  stage(1, 64);
  int cur = 0;
  for (int k0 = 0; k0 < 1024; k0 += 64) {
    if (k0 + 64 < 1024) wait_vm<6>(); else wait_vm<0>();
    __builtin_amdgcn_s_barrier();
    __builtin_amdgcn_sched_barrier(0);
    const char* sAc = (const char*)(sAp + cur * 8192);
    const char* sBc = (const char*)(sBp + cur * 4096);
    short8 af[2][2], bfr[4][2];
#pragma unroll
    for (int mi = 0; mi < 2; ++mi) {
      int arow = wave * 32 + mi * 16 + fr;
      int asw = (arow & 7) << 4;
#pragma unroll
      for (int kc = 0; kc < 2; ++kc)
        af[mi][kc] = *(const short8*)(sAc + arow * 128 + ((kc * 64 + fq * 16) ^ asw));
    }
#pragma unroll
    for (int ni = 0; ni < 4; ++ni) {
      int brow = ni * 16 + fr;
      int bsw = (brow & 7) << 4;
#pragma unroll
      for (int kc = 0; kc < 2; ++kc)
        bfr[ni][kc] = *(const short8*)(sBc + brow * 128 + ((kc * 64 + fq * 16) ^ bsw));
    }
#pragma unroll
    for (int mi = 0; mi < 2; ++mi)
#pragma unroll
      for (int ni = 0; ni < 4; ++ni)
#pragma unroll
        for (int kc = 0; kc < 2; ++kc)
          acc[mi][ni] = __builtin_amdgcn_mfma_f32_16x16x32_bf16(af[mi][kc], bfr[ni][kc],
                                                               acc[mi][ni], 0, 0, 0);
    __builtin_amdgcn_sched_barrier(0);
    __builtin_amdgcn_s_barrier();
    if (k0 + 128 < 1024) stage(cur, k0 + 128);
    cur ^= 1;
  }

#pragma unroll
  for (int ni = 0; ni < 4; ++ni) {
    int n = n0 + ni * 16 + fr;
    float bi = bias[n];
#pragma unroll
    for (int mi = 0; mi < 2; ++mi)
#pragma unroll
      for (int j = 0; j < 4; ++j) {
        int m = m0 + wave * 32 + mi * 16 + fq * 4 + j;
        Cf[(size_t)m * 1024 + n] = acc[mi][ni][j] + bi;
      }
  }
}

// ---------------- causal flash attention (r11 schedule, VALU diet) ----------------
// grid 1024 (1D), balanced permutation + letter flip. Swapped-QK in-register
// softmax; scores arrive pre-scaled (scl2 folded into Q). Hoisted LDS offsets
// (shared by K and V reads), v_perm packs. 32KB LDS.
__global__ __launch_bounds__(256, 5) void attn_kernel(
    const bf16* __restrict__ qb, const bf16* __restrict__ kb, const bf16* __restrict__ vt,
    unsigned short* __restrict__ out) {
  __shared__ bf16 sK[2][64 * 64];   // [kv][d], 128B rows, swz (row&7)<<4
  __shared__ bf16 sV[2][64 * 64];   // [d][pos], 128B rows, swz (row&7)<<4
  const int bid = blockIdx.x;
  const int rr4 = bid >> 8, g = bid & 255, jj = g & 31;
  const int xq = (rr4 & 1) ? (31 - jj) : jj;
  const int bh = (g >> 5) + 8 * rr4;
  const int q0A = xq * 32, q0B = (63 - xq) * 32;
  const int tid = threadIdx.x;
  const int lane = tid & 63, wave = tid >> 6;
  const int fr = lane & 15, fq = lane >> 4;
  const int myq0 = ((((wave >> 1) ^ bid) & 1)) ? q0B : q0A;  // letter flip
  const int base = myq0 + (wave & 1) * 16;

  const size_t qrow = (size_t)bh * 2048 + base + fr;
  short8 qf0 = *(const short8*)(qb + qrow * 64 + fq * 8);
  short8 qf1 = *(const short8*)(qb + qrow * 64 + 32 + fq * 8);
  asm volatile("" : "+v"(qf0), "+v"(qf1));
  __builtin_amdgcn_sched_barrier(0);

  const bf16* kgb = kb + (size_t)bh * 2048 * 64;
  const bf16* vgb = vt + (size_t)bh * 64 * 2048;

  auto stage = [&](int buf, int t0) {
#pragma unroll
    for (int call = 0; call < 2; ++call) {
      int row = call * 32 + (tid >> 3);
      int sb = ((tid & 7) * 16) ^ ((row & 7) << 4);
      gload_lds16(kgb + (size_t)(t0 + row) * 64 + sb / 2,
                  &sK[buf][call * 2048 + wave * 512]);
    }
#pragma unroll
    for (int call = 0; call < 2; ++call) {
      int row = call * 32 + (tid >> 3);
      int sb = ((tid & 7) * 16) ^ ((row & 7) << 4);
      gload_lds16(vgb + (size_t)row * 2048 + t0 + sb / 2,
                  &sV[buf][call * 2048 + wave * 512]);
    }
  };

  floatx4 oacc[4] = {};
  float m_l = -INFINITY, l_l = 0.f;
  const int qrow_l = base + fr;
  const int rowq = base + fq * 4;
  const int sw = (fr & 7) << 4;

  // hoisted LDS byte offsets — identical formula serves K and V fragments.
  int off[4][2];
#pragma unroll
  for (int c = 0; c < 4; ++c) {
#pragma unroll
    for (int kc = 0; kc < 2; ++kc)
      off[c][kc] = (c * 16 + fr) * 128 + ((kc * 64 + fq * 16) ^ sw);
    asm volatile("" : "+v"(off[c][0]), "+v"(off[c][1]));
  }
  __builtin_amdgcn_sched_barrier(0);

  const int tEnd = q0B + 32;
  stage(0, 0);
  stage(1, 64);
  int cur = 0;
  for (int t0 = 0; t0 < tEnd; t0 += 64) {
    if (t0 + 64 < tEnd) wait_vm<4>(); else wait_vm<0>();
    __builtin_amdgcn_s_barrier();
    __builtin_amdgcn_sched_barrier(0);
    if (t0 < myq0 + 32) {
      const char* sKc = (const char*)sK[cur];
      const char* sVc = (const char*)sV[cur];
      floatx4 sacc[4] = {};
      __builtin_amdgcn_s_setprio(1);
#pragma unroll
      for (int c = 0; c < 4; ++c) {
        short8 kf0 = *(const short8*)(sKc + off[c][0]);
        short8 kf1 = *(const short8*)(sKc + off[c][1]);
        // SWAPPED: A=K (rows=kv), B=Q (rows=q) -> C[kv][q], col=fr=q
        sacc[c] = __builtin_amdgcn_mfma_f32_16x16x32_bf16(kf0, qf0, sacc[c], 0, 0, 0);
        sacc[c] = __builtin_amdgcn_mfma_f32_16x16x32_bf16(kf1, qf1, sacc[c], 0, 0, 0);
      }
      __builtin_amdgcn_s_setprio(0);
      if (t0 + 63 > base) {  // causal mask: kv = t0+16c+4fq+r vs q = base+fr
#pragma unroll
        for (int c = 0; c < 4; ++c)
#pragma unroll
          for (int r = 0; r < 4; ++r)
            if ((t0 + c * 16 + fq * 4 + r) > qrow_l) sacc[c][r] = -1e30f;
      }
      float pm0 = fmaxf(fmaxf(sacc[0][0], sacc[0][1]), fmaxf(sacc[0][2], sacc[0][3]));
      float pm1 = fmaxf(fmaxf(sacc[1][0], sacc[1][1]), fmaxf(sacc[1][2], sacc[1][3]));
      float pm2 = fmaxf(fmaxf(sacc[2][0], sacc[2][1]), fmaxf(sacc[2][2], sacc[2][3]));
      float pm3 = fmaxf(fmaxf(sacc[3][0], sacc[3][1]), fmaxf(sacc[3][2], sacc[3][3]));
      float pm = fmaxf(fmaxf(pm0, pm1), fmaxf(pm2, pm3));
      if (!__all(pm - m_l <= 11.5f)) {
        float pmr = fmaxf(pm, __shfl_xor(pm, 16));
        pmr = fmaxf(pmr, __shfl_xor(pmr, 32));
        float mnew = fmaxf(m_l, pmr);
        float rs = EXP2(m_l - mnew);
        m_l = mnew;
        l_l *= rs;
        float rsr[4];
#pragma unroll
        for (int r = 0; r < 4; ++r) rsr[r] = __shfl(rs, rowq - base + r);
#pragma unroll
        for (int d = 0; d < 4; ++d)
#pragma unroll
          for (int r = 0; r < 4; ++r) oacc[d][r] *= rsr[r];
      }
      float p[4][4];
      float ssum = 0.f;
#pragma unroll
      for (int c = 0; c < 4; ++c)
#pragma unroll
        for (int r = 0; r < 4; ++r) {
          p[c][r] = EXP2(sacc[c][r] - m_l);
          ssum += p[c][r];
        }
      ssum += __shfl_xor(ssum, 16);
      ssum += __shfl_xor(ssum, 32);
      l_l += ssum;
      short8 pf[2];
#pragma unroll
      for (int kc = 0; kc < 2; ++kc) {
        union { unsigned int w[4]; short8 v; } pk;
        pk.w[0] = pack_bf16(p[kc][0], p[kc][1]);
        pk.w[1] = pack_bf16(p[kc][2], p[kc][3]);
        pk.w[2] = pack_bf16(p[kc + 2][0], p[kc + 2][1]);
        pk.w[3] = pack_bf16(p[kc + 2][2], p[kc + 2][3]);
        pf[kc] = pk.v;
      }
      __builtin_amdgcn_s_setprio(1);
#pragma unroll
      for (int d = 0; d < 4; ++d) {
#pragma unroll
        for (int kc = 0; kc < 2; ++kc) {
          short8 vf = *(const short8*)(sVc + off[d][kc]);
          oacc[d] = __builtin_amdgcn_mfma_f32_16x16x32_bf16(pf[kc], vf, oacc[d], 0, 0, 0);
        }
      }
      __builtin_amdgcn_s_setprio(0);
    }
    __builtin_amdgcn_sched_barrier(0);
    __builtin_amdgcn_s_barrier();
    if (t0 + 128 < tEnd) stage(cur, t0 + 128);
    cur ^= 1;
  }
  const int b = bh >> 4, h = bh & 15;
  float il[4];
#pragma unroll
  for (int r = 0; r < 4; ++r) il[r] = 1.0f / __shfl(l_l, rowq - base + r);
#pragma unroll
  for (int r = 0; r < 4; ++r)
#pragma unroll
    for (int d = 0; d < 4; ++d) {
      size_t o = ((size_t)b * 2048 + rowq + r) * 1024 + h * 64 + d * 16 + fr;
      out[o] = bfbits(oacc[d][r] * il[r]);
    }
}

extern "C" void kernel_launch(void* const* d_in, const int* in_sizes, int n_in,
                              void* d_out, int out_size, void* d_ws, size_t ws_size,
                              hipStream_t stream) {
  (void)in_sizes; (void)n_in; (void)out_size; (void)ws_size;
  const float* x  = (const float*)d_in[0];
  const float* Wq = (const float*)d_in[1];
  const float* bq = (const float*)d_in[2];
  const float* Wk = (const float*)d_in[3];
  const float* bk = (const float*)d_in[4];
  const float* Wv = (const float*)d_in[5];
  const float* bv = (const float*)d_in[6];
  const float* Wo = (const float*)d_in[7];
  const float* bo = (const float*)d_in[8];
  const float* lsc = (const float*)d_in[9];

  uint8_t* w = (uint8_t*)d_ws;
  const size_t MB = 1ull << 20;
  bf16* xb   = (bf16*)(w + 0);          // 8 MB
  bf16* wqb  = (bf16*)(w + 8 * MB);
  bf16* wkb  = (bf16*)(w + 10 * MB);
  bf16* wvb  = (bf16*)(w + 12 * MB);
  bf16* wob  = (bf16*)(w + 14 * MB);
  bf16* qbn  = (bf16*)(w + 16 * MB);    // [B,H,S,64] (Q pre-scaled)
  bf16* kbn  = (bf16*)(w + 24 * MB);
  bf16* vtb  = (bf16*)(w + 32 * MB);    // [B,H,64,S] (kv-permuted cols)
  bf16* atb  = (bf16*)(w + 40 * MB);    // [B,S,DIM]
  float* tc  = (float*)(w + 48 * MB);
  float* ts  = (float*)(w + 48 * MB + 256 * 1024);

  prep_kernel<<<8448, 256, 0, stream>>>(
      x, Wq, Wk, Wv, Wo, (unsigned short*)xb,
      (unsigned short*)wqb, (unsigned short*)wkb, (unsigned short*)wvb,
      (unsigned short*)wob, tc, ts);

  qkv_kernel<<<dim3(32, 24), 256, 0, stream>>>(
      xb, wqb, wkb, wvb, bq, bk, bv, tc, ts, lsc,
      (unsigned short*)qbn, (unsigned short*)kbn, (unsigned short*)vtb);

  attn_kernel<<<1024, 256, 0, stream>>>(qbn, kbn, vtb, (unsigned short*)atb);

  gemm_bt_kernel<<<dim3(32, 16), 256, 0, stream>>>(atb, wob, bo, (float*)d_out);
}

// Round 18
// 108.284 us; speedup vs baseline: 1.0113x; 1.0113x over previous
//
#include <hip/hip_runtime.h>
#include <hip/hip_bf16.h>
#include <math.h>

typedef __hip_bfloat16 bf16;
typedef __attribute__((ext_vector_type(8))) short short8;
typedef __attribute__((ext_vector_type(4))) float floatx4;

static constexpr int Bn = 2, Sn = 2048, Hn = 16, DHn = 64, DIMn = 1024;
static constexpr int Mn = Bn * Sn;  // 4096 tokens

#if __has_builtin(__builtin_amdgcn_exp2f)
#define EXP2(x) __builtin_amdgcn_exp2f(x)
#else
#define EXP2(x) exp2f(x)
#endif

__device__ __forceinline__ unsigned short bfbits(float f) {
  union { __hip_bfloat16 h; unsigned short u; } cv;
  cv.h = __float2bfloat16(f);
  return cv.u;
}

__device__ __forceinline__ float bf2f(unsigned short u) {
  union { float f; unsigned int u; } cv;
  cv.u = ((unsigned int)u) << 16;
  return cv.f;
}

// truncate-pack two f32 to a bf16-pair dword (lo in low half)
__device__ __forceinline__ unsigned int pack_bf16(float lo, float hi) {
  union { float f; unsigned int u; } a, b;
  a.f = lo; b.f = hi;
  return (b.u & 0xFFFF0000u) | (a.u >> 16);
}

// async global->LDS, 16B per lane. dst is wave-uniform base; HW adds lane*16.
__device__ __forceinline__ void gload_lds16(const void* g, void* l) {
  __builtin_amdgcn_global_load_lds(
      (const __attribute__((address_space(1))) uint32_t*)g,
      (__attribute__((address_space(3))) uint32_t*)l, 16, 0, 0);
}

// counted waits (T4). sched_barrier pins per rule #18.
template <int N>
__device__ __forceinline__ void wait_vm() {
  if constexpr (N == 0) asm volatile("s_waitcnt vmcnt(0)" ::: "memory");
  else if constexpr (N == 2) asm volatile("s_waitcnt vmcnt(2)" ::: "memory");
  else if constexpr (N == 3) asm volatile("s_waitcnt vmcnt(3)" ::: "memory");
  else if constexpr (N == 4) asm volatile("s_waitcnt vmcnt(4)" ::: "memory");
  else asm volatile("s_waitcnt vmcnt(6)" ::: "memory");
  __builtin_amdgcn_sched_barrier(0);
}

// ---------------- fused prep: x->bf16 | 4 weights->bf16 | rope tables ----------------
__global__ void prep_kernel(const float* __restrict__ x,
                            const float* __restrict__ a0, const float* __restrict__ a1,
                            const float* __restrict__ a2, const float* __restrict__ a3,
                            unsigned short* __restrict__ xo,
                            unsigned short* __restrict__ o0, unsigned short* __restrict__ o1,
                            unsigned short* __restrict__ o2, unsigned short* __restrict__ o3,
                            float* __restrict__ tc, float* __restrict__ ts) {
  const int bid = blockIdx.x;
  if (bid < 8192) {
    const float* s;
    unsigned short* d;
    int i;
    if (bid < 4096) {
      s = x; d = xo; i = bid * 256 + threadIdx.x;
    } else {
      int wsel = (bid - 4096) >> 10;
      s = (wsel == 0) ? a0 : (wsel == 1) ? a1 : (wsel == 2) ? a2 : a3;
      d = (wsel == 0) ? o0 : (wsel == 1) ? o1 : (wsel == 2) ? o2 : o3;
      i = ((bid - 4096) & 1023) * 256 + threadIdx.x;
    }
    float4 v = ((const float4*)s)[i];
    ushort4 o;
    o.x = bfbits(v.x); o.y = bfbits(v.y); o.z = bfbits(v.z); o.w = bfbits(v.w);
    ((ushort4*)d)[i] = o;
  } else {
    int t = (bid - 8192) * 256 + threadIdx.x;  // 2048*32 = 65536
    int pos = t >> 5, i = t & 31;
    float f = powf(10000.0f, -(float)i * (1.0f / 32.0f));
    float a = (float)pos * f;
    tc[t] = cosf(a);
    ts[t] = sinf(a);
  }
}

// ---------------- fused QKV GEMM + RoPE + l2norm: 128m x 128n (2 heads) ----------------
// BK=64, 128B LDS rows, XOR-swizzled (zero-conflict). grid (32, 24):
// sel = y>>3, n0 = (y&7)*128 = two heads. A double-buffered (depth-2),
// B single-buffered (staged after barrier-2, consumed next iter).
// LDS = 32KB(A) + 16KB(B) = 48KB -> 3 blocks/CU. 32 MFMA / 20 ds_read per
// K-step, half the barriers per MFMA of the 128x64 version.
__global__ __launch_bounds__(256, 3) void qkv_kernel(
    const bf16* __restrict__ A,
    const bf16* __restrict__ Wq, const bf16* __restrict__ Wk, const bf16* __restrict__ Wv,
    const float* __restrict__ bq, const float* __restrict__ bk, const float* __restrict__ bv,
    const float* __restrict__ tc, const float* __restrict__ ts,
    unsigned short* __restrict__ qo, unsigned short* __restrict__ ko,
    unsigned short* __restrict__ vt) {
  __shared__ bf16 smem[24576];  // sA[2][8192] 32KB | sB[8192] 16KB; ct reuses sA
  bf16* sAp = smem;
  bf16* sBp = smem + 16384;
  const int sel = blockIdx.y >> 3;
  const bf16* Bw = (sel == 0) ? Wq : (sel == 1) ? Wk : Wv;
  const float* bias = (sel == 0) ? bq : (sel == 1) ? bk : bv;
  const int tid = threadIdx.x;
  const int lane = tid & 63, wave = tid >> 6;
  const int fr = lane & 15, fq = lane >> 4;
  const int m0 = blockIdx.x * 128, n0 = (blockIdx.y & 7) * 128;

  floatx4 acc[2][8] = {};  // [mi][ni]; wave rows: wave*32 + mi*16 + ...

  auto stageA = [&](int buf, int k0) {
#pragma unroll
    for (int call = 0; call < 4; ++call) {
      int row = call * 32 + (tid >> 3);
      int sb = ((tid & 7) * 16) ^ ((row & 7) << 4);
      gload_lds16(A + (size_t)(m0 + row) * 1024 + k0 + sb / 2,
                  sAp + buf * 8192 + call * 2048 + wave * 512);
    }
  };
  auto stageB = [&](int k0) {
#pragma unroll
    for (int call = 0; call < 4; ++call) {
      int row = call * 32 + (tid >> 3);
      int sb = ((tid & 7) * 16) ^ ((row & 7) << 4);
      gload_lds16(Bw + (size_t)(n0 + row) * 1024 + k0 + sb / 2,
                  sBp + call * 2048 + wave * 512);
    }
  };

  stageB(0);        // oldest
  stageA(0, 0);
  stageA(1, 64);    // newest 4
  int cur = 0;
  for (int k0 = 0; k0 < 1024; k0 += 64) {
    if (k0 + 64 < 1024) wait_vm<4>(); else wait_vm<0>();
    __builtin_amdgcn_s_barrier();
    __builtin_amdgcn_sched_barrier(0);
    const char* sAc = (const char*)(sAp + cur * 8192);
    const char* sBc = (const char*)sBp;
    short8 af[2][2];
#pragma unroll
    for (int mi = 0; mi < 2; ++mi) {
      int arow = wave * 32 + mi * 16 + fr;
      int asw = (arow & 7) << 4;
#pragma unroll
      for (int kc = 0; kc < 2; ++kc)
        af[mi][kc] = *(const short8*)(sAc + arow * 128 + ((kc * 64 + fq * 16) ^ asw));
    }
#pragma unroll
    for (int nh = 0; nh < 2; ++nh) {  // two ni-halves: caps live B-frag regs
      short8 bfr[4][2];
#pragma unroll
      for (int n4 = 0; n4 < 4; ++n4) {
        int brow = (nh * 4 + n4) * 16 + fr;
        int bsw = (brow & 7) << 4;
#pragma unroll
        for (int kc = 0; kc < 2; ++kc)
          bfr[n4][kc] = *(const short8*)(sBc + brow * 128 + ((kc * 64 + fq * 16) ^ bsw));
      }
#pragma unroll
      for (int mi = 0; mi < 2; ++mi)
#pragma unroll
        for (int n4 = 0; n4 < 4; ++n4)
#pragma unroll
          for (int kc = 0; kc < 2; ++kc)
            acc[mi][nh * 4 + n4] = __builtin_amdgcn_mfma_f32_16x16x32_bf16(
                af[mi][kc], bfr[n4][kc], acc[mi][nh * 4 + n4], 0, 0, 0);
    }
    __builtin_amdgcn_sched_barrier(0);
    __builtin_amdgcn_s_barrier();
    if (k0 + 64 < 1024) stageB(k0 + 64);     // depth-1 (older than A below)
    if (k0 + 128 < 1024) stageA(cur, k0 + 128);  // depth-2 (newest 4)
    cur ^= 1;
  }

  if (sel < 2) {
    // fused bias + RoPE + l2norm epilogue (f32) per head; write [B,H,S,64]
    unsigned short* dst = (sel == 0) ? qo : ko;
    const int h0 = n0 >> 6;
    float bias_d[8];
#pragma unroll
    for (int ni = 0; ni < 8; ++ni) bias_d[ni] = bias[n0 + ni * 16 + fr];
#pragma unroll
    for (int mi = 0; mi < 2; ++mi)
#pragma unroll
      for (int j = 0; j < 4; ++j) {
        int m = m0 + wave * 32 + mi * 16 + fq * 4 + j;
        int b = m >> 11, srow = m & 2047;
#pragma unroll
        for (int hh = 0; hh < 2; ++hh) {
          float y[4], ss = 0.f;
#pragma unroll
          for (int n4 = 0; n4 < 4; ++n4) {
            int ni = hh * 4 + n4;
            float val = acc[mi][ni][j] + bias_d[ni];
            float prt = __shfl_xor(val, 1);
            int d = n4 * 16 + fr;  // dim within head
            int jj = d >> 1;
            float cc = tc[srow * 32 + jj], sn = ts[srow * 32 + jj];
            y[n4] = (d & 1) ? (val * cc + prt * sn) : (val * cc - prt * sn);
            ss += y[n4] * y[n4];
          }
          ss += __shfl_xor(ss, 1);
          ss += __shfl_xor(ss, 2);
          ss += __shfl_xor(ss, 4);
          ss += __shfl_xor(ss, 8);
          float inv = rsqrtf(ss + 1e-6f);
          size_t ob = ((size_t)(b * 16 + h0 + hh) * 2048 + srow) * 64;
#pragma unroll
          for (int n4 = 0; n4 < 4; ++n4)
            dst[ob + n4 * 16 + fr] = bfbits(y[n4] * inv);
        }
      }
  } else {
    // V: transpose through LDS (256B rows), kv-permuted store per 64-group.
    __syncthreads();
    char* ct = (char*)smem;  // [nl 128][ml 128] bf16, 256B rows, ^=(nl&15)<<4 (32KB)
#pragma unroll
    for (int mi = 0; mi < 2; ++mi)
#pragma unroll
      for (int ni = 0; ni < 8; ++ni) {
        int nl = ni * 16 + fr;
        float bi = bias[n0 + nl];
#pragma unroll
        for (int j = 0; j < 4; j += 2) {
          int ml = wave * 32 + mi * 16 + fq * 4 + j;
          unsigned int u = (unsigned int)bfbits(acc[mi][ni][j] + bi) |
                           ((unsigned int)bfbits(acc[mi][ni][j + 1] + bi) << 16);
          *(unsigned int*)(ct + nl * 256 + ((ml * 2) ^ ((nl & 15) << 4))) = u;
        }
      }
    __syncthreads();
    int nl2 = tid >> 1, half = tid & 1;  // 128 rows x 2 threads (one 64-group each)
    int head = (n0 >> 6) + (nl2 >> 6), dd = nl2 & 63;
    int b = m0 >> 11, s0 = m0 & 2047;
    unsigned short* orow =
        vt + (((size_t)b * 16 + head) * 64 + dd) * 2048 + s0 + half * 64;
    int swz = (nl2 & 15) << 4;
    const char* rowp = ct + nl2 * 256;
#pragma unroll
    for (int ch = 0; ch < 4; ++ch) {
      int cb = half * 128 + 32 * (ch >> 1) + 16 * (ch & 1);
      union { long long l[2]; short8 v; } s1, s2;
      s1.l[0] = *(const long long*)(rowp + ((cb) ^ swz));
      s1.l[1] = *(const long long*)(rowp + ((cb + 64) ^ swz));
      s2.l[0] = *(const long long*)(rowp + ((cb + 8) ^ swz));
      s2.l[1] = *(const long long*)(rowp + ((cb + 72) ^ swz));
      *(short8*)(orow + ch * 16) = s1.v;
      *(short8*)(orow + ch * 16 + 8) = s2.v;
    }
  }
}

// ---------------- Wo GEMM: 128m x 64n tiles, BK=64, swizzled, f32 out ----------------
__global__ __launch_bounds__(256, 3) void gemm_bt_kernel(
    const bf16* __restrict__ A, const bf16* __restrict__ Bw,
    const float* __restrict__ bias, float* __restrict__ Cf) {
  __shared__ bf16 smem[24576];  // sA[2][8192] | sB[2][4096]
  bf16* sAp = smem;
  bf16* sBp = smem + 16384;
  const int tid = threadIdx.x;
  const int lane = tid & 63, wave = tid >> 6;
  const int fr = lane & 15, fq = lane >> 4;
  const int m0 = blockIdx.x * 128, n0 = blockIdx.y * 64;

  floatx4 acc[2][4] = {};

  auto stage = [&](int buf, int k0) {
#pragma unroll
    for (int call = 0; call < 4; ++call) {
      int row = call * 32 + (tid >> 3);
      int sb = ((tid & 7) * 16) ^ ((row & 7) << 4);
      gload_lds16(A + (size_t)(m0 + row) * 1024 + k0 + sb / 2,
                  sAp + buf * 8192 + call * 2048 + wave * 512);
    }
#pragma unroll
    for (int call = 0; call < 2; ++call) {
      int row = call * 32 + (tid >> 3);
      int sb = ((tid & 7) * 16) ^ ((row & 7) << 4);
      gload_lds16(Bw + (size_t)(n0 + row) * 1024 + k0 + sb / 2,
                  sBp + buf * 4096 + call * 2048 + wave * 512);
    }
  };

  stage(0, 0);
  stage(1, 64);
  int cur = 0;
  for (int k0 = 0; k0 < 1024; k0 += 64) {
    if (k0 + 64 < 1024) wait_vm<6>(); else wait_vm<0>();
    __builtin_amdgcn_s_barrier();
    __builtin_amdgcn_sched_barrier(0);
    const char* sAc = (const char*)(sAp + cur * 8192);
    const char* sBc = (const char*)(sBp + cur * 4096);
    short8 af[2][2], bfr[4][2];
#pragma unroll
    for (int mi = 0; mi < 2; ++mi) {
      int arow = wave * 32 + mi * 16 + fr;
      int asw = (arow & 7) << 4;
#pragma unroll
      for (int kc = 0; kc < 2; ++kc)
        af[mi][kc] = *(const short8*)(sAc + arow * 128 + ((kc * 64 + fq * 16) ^ asw));
    }
#pragma unroll
    for (int ni = 0; ni < 4; ++ni) {
      int brow = ni * 16 + fr;
      int bsw = (brow & 7) << 4;
#pragma unroll
      for (int kc = 0; kc < 2; ++kc)
        bfr[ni][kc] = *(const short8*)(sBc + brow * 128 + ((kc * 64 + fq * 16) ^ bsw));
    }
#pragma unroll
    for (int mi = 0; mi < 2; ++mi)
#pragma unroll
      for (int ni = 0; ni < 4; ++ni)
#pragma unroll
        for (int kc = 0; kc < 2; ++kc)
          acc[mi][ni] = __builtin_amdgcn_mfma_f32_16x16x32_bf16(af[mi][kc], bfr[ni][kc],
                                                               acc[mi][ni], 0, 0, 0);
    __builtin_amdgcn_sched_barrier(0);
    __builtin_amdgcn_s_barrier();
    if (k0 + 128 < 1024) stage(cur, k0 + 128);
    cur ^= 1;
  }

#pragma unroll
  for (int ni = 0; ni < 4; ++ni) {
    int n = n0 + ni * 16 + fr;
    float bi = bias[n];
#pragma unroll
    for (int mi = 0; mi < 2; ++mi)
#pragma unroll
      for (int j = 0; j < 4; ++j) {
        int m = m0 + wave * 32 + mi * 16 + fq * 4 + j;
        Cf[(size_t)m * 1024 + n] = acc[mi][ni][j] + bi;
      }
  }
}

// ---------------- causal flash attention (r11 structure — best measured) ----------------
// grid 1024 (1D), balanced permutation + letter flip. Swapped-QK in-register
// softmax; V global layout kv-permuted so PV B-fragment is one conflict-free
// ds_read_b128. global_load_lds staging, 2-buf, counted vmcnt. 32KB LDS.
__global__ __launch_bounds__(256, 5) void attn_kernel(
    const bf16* __restrict__ qb, const bf16* __restrict__ kb, const bf16* __restrict__ vt,
    const float* __restrict__ ls, unsigned short* __restrict__ out) {
  __shared__ bf16 sK[2][64 * 64];   // [kv][d], 128B rows, swz (row&7)<<4
  __shared__ bf16 sV[2][64 * 64];   // [d][pos], 128B rows, swz (row&7)<<4
  const int bid = blockIdx.x;
  const int rr4 = bid >> 8, g = bid & 255, jj = g & 31;
  const int xq = (rr4 & 1) ? (31 - jj) : jj;
  const int bh = (g >> 5) + 8 * rr4;
  const int q0A = xq * 32, q0B = (63 - xq) * 32;
  const int tid = threadIdx.x;
  const int lane = tid & 63, wave = tid >> 6;
  const int fr = lane & 15, fq = lane >> 4;
  const int myq0 = ((((wave >> 1) ^ bid) & 1)) ? q0B : q0A;  // letter flip
  const int base = myq0 + (wave & 1) * 16;
  float scl2 = __expf(ls[0]) * 0.125f * 1.44269504f;

  const size_t qrow = (size_t)bh * 2048 + base + fr;
  short8 qf0 = *(const short8*)(qb + qrow * 64 + fq * 8);
  short8 qf1 = *(const short8*)(qb + qrow * 64 + 32 + fq * 8);
  asm volatile("" : "+v"(qf0), "+v"(qf1), "+v"(scl2));
  __builtin_amdgcn_sched_barrier(0);

  const bf16* kgb = kb + (size_t)bh * 2048 * 64;
  const bf16* vgb = vt + (size_t)bh * 64 * 2048;

  auto stage = [&](int buf, int t0) {
#pragma unroll
    for (int call = 0; call < 2; ++call) {
      int row = call * 32 + (tid >> 3);
      int sb = ((tid & 7) * 16) ^ ((row & 7) << 4);
      gload_lds16(kgb + (size_t)(t0 + row) * 64 + sb / 2,
                  &sK[buf][call * 2048 + wave * 512]);
    }
#pragma unroll
    for (int call = 0; call < 2; ++call) {
      int row = call * 32 + (tid >> 3);
      int sb = ((tid & 7) * 16) ^ ((row & 7) << 4);
      gload_lds16(vgb + (size_t)row * 2048 + t0 + sb / 2,
                  &sV[buf][call * 2048 + wave * 512]);
    }
  };

  floatx4 oacc[4] = {};
  float m_l = -INFINITY, l_l = 0.f;
  const int qrow_l = base + fr;
  const int rowq = base + fq * 4;
  const int sw = (fr & 7) << 4;

  const int tEnd = q0B + 32;
  stage(0, 0);
  stage(1, 64);
  int cur = 0;
  for (int t0 = 0; t0 < tEnd; t0 += 64) {
    if (t0 + 64 < tEnd) wait_vm<4>(); else wait_vm<0>();
    __builtin_amdgcn_s_barrier();
    __builtin_amdgcn_sched_barrier(0);
    if (t0 < myq0 + 32) {
      const char* sKc = (const char*)sK[cur];
      const char* sVc = (const char*)sV[cur];
      floatx4 sacc[4] = {};
      __builtin_amdgcn_s_setprio(1);
#pragma unroll
      for (int c = 0; c < 4; ++c) {
        int rb = (c * 16 + fr) * 128;
        short8 kf0 = *(const short8*)(sKc + rb + ((fq * 16) ^ sw));
        short8 kf1 = *(const short8*)(sKc + rb + ((64 + fq * 16) ^ sw));
        // SWAPPED: A=K (rows=kv), B=Q (rows=q) -> C[kv][q], col=fr=q
        sacc[c] = __builtin_amdgcn_mfma_f32_16x16x32_bf16(kf0, qf0, sacc[c], 0, 0, 0);
        sacc[c] = __builtin_amdgcn_mfma_f32_16x16x32_bf16(kf1, qf1, sacc[c], 0, 0, 0);
      }
      __builtin_amdgcn_s_setprio(0);
      if (t0 + 63 > base) {  // causal mask: kv = t0+16c+4fq+r vs q = base+fr
#pragma unroll
        for (int c = 0; c < 4; ++c)
#pragma unroll
          for (int r = 0; r < 4; ++r)
            if ((t0 + c * 16 + fq * 4 + r) > qrow_l) sacc[c][r] = -1e30f;
      }
      float pm0 = fmaxf(fmaxf(sacc[0][0], sacc[0][1]), fmaxf(sacc[0][2], sacc[0][3]));
      float pm1 = fmaxf(fmaxf(sacc[1][0], sacc[1][1]), fmaxf(sacc[1][2], sacc[1][3]));
      float pm2 = fmaxf(fmaxf(sacc[2][0], sacc[2][1]), fmaxf(sacc[2][2], sacc[2][3]));
      float pm3 = fmaxf(fmaxf(sacc[3][0], sacc[3][1]), fmaxf(sacc[3][2], sacc[3][3]));
      float pm = fmaxf(fmaxf(pm0, pm1), fmaxf(pm2, pm3));
      if (!__all(pm * scl2 - m_l <= 11.5f)) {
        float pmr = fmaxf(pm, __shfl_xor(pm, 16));
        pmr = fmaxf(pmr, __shfl_xor(pmr, 32));
        float mnew = fmaxf(m_l, pmr * scl2);
        float rs = EXP2(m_l - mnew);
        m_l = mnew;
        l_l *= rs;
        float rsr[4];
#pragma unroll
        for (int r = 0; r < 4; ++r) rsr[r] = __shfl(rs, rowq - base + r);
#pragma unroll
        for (int d = 0; d < 4; ++d)
#pragma unroll
          for (int r = 0; r < 4; ++r) oacc[d][r] *= rsr[r];
      }
      float p[4][4];
      float ssum = 0.f;
#pragma unroll
      for (int c = 0; c < 4; ++c)
#pragma unroll
        for (int r = 0; r < 4; ++r) {
          p[c][r] = EXP2(sacc[c][r] * scl2 - m_l);
          ssum += p[c][r];
        }
      ssum += __shfl_xor(ssum, 16);
      ssum += __shfl_xor(ssum, 32);
      l_l += ssum;
      short8 pf[2];
#pragma unroll
      for (int kc = 0; kc < 2; ++kc) {
        union { unsigned int w[4]; short8 v; } pk;
        pk.w[0] = pack_bf16(p[kc][0], p[kc][1]);
        pk.w[1] = pack_bf16(p[kc][2], p[kc][3]);
        pk.w[2] = pack_bf16(p[kc + 2][0], p[kc + 2][1]);
        pk.w[3] = pack_bf16(p[kc + 2][2], p[kc + 2][3]);
        pf[kc] = pk.v;
      }
      __builtin_amdgcn_s_setprio(1);
#pragma unroll
      for (int d = 0; d < 4; ++d) {
        int rbv = (d * 16 + fr) * 128;
#pragma unroll
        for (int kc = 0; kc < 2; ++kc) {
          short8 vf = *(const short8*)(sVc + rbv + ((kc * 64 + fq * 16) ^ sw));
          oacc[d] = __builtin_amdgcn_mfma_f32_16x16x32_bf16(pf[kc], vf, oacc[d], 0, 0, 0);
        }
      }
      __builtin_amdgcn_s_setprio(0);
    }
    __builtin_amdgcn_sched_barrier(0);
    __builtin_amdgcn_s_barrier();
    if (t0 + 128 < tEnd) stage(cur, t0 + 128);
    cur ^= 1;
  }
  const int b = bh >> 4, h = bh & 15;
  float il[4];
#pragma unroll
  for (int r = 0; r < 4; ++r) il[r] = 1.0f / __shfl(l_l, rowq - base + r);
#pragma unroll
  for (int r = 0; r < 4; ++r)
#pragma unroll
    for (int d = 0; d < 4; ++d) {
      size_t o = ((size_t)b * 2048 + rowq + r) * 1024 + h * 64 + d * 16 + fr;
      out[o] = bfbits(oacc[d][r] * il[r]);
    }
}

extern "C" void kernel_launch(void* const* d_in, const int* in_sizes, int n_in,
                              void* d_out, int out_size, void* d_ws, size_t ws_size,
                              hipStream_t stream) {
  (void)in_sizes; (void)n_in; (void)out_size; (void)ws_size;
  const float* x  = (const float*)d_in[0];
  const float* Wq = (const float*)d_in[1];
  const float* bq = (const float*)d_in[2];
  const float* Wk = (const float*)d_in[3];
  const float* bk = (const float*)d_in[4];
  const float* Wv = (const float*)d_in[5];
  const float* bv = (const float*)d_in[6];
  const float* Wo = (const float*)d_in[7];
  const float* bo = (const float*)d_in[8];
  const float* lsc = (const float*)d_in[9];

  uint8_t* w = (uint8_t*)d_ws;
  const size_t MB = 1ull << 20;
  bf16* xb   = (bf16*)(w + 0);          // 8 MB
  bf16* wqb  = (bf16*)(w + 8 * MB);
  bf16* wkb  = (bf16*)(w + 10 * MB);
  bf16* wvb  = (bf16*)(w + 12 * MB);
  bf16* wob  = (bf16*)(w + 14 * MB);
  bf16* qbn  = (bf16*)(w + 16 * MB);    // [B,H,S,64]
  bf16* kbn  = (bf16*)(w + 24 * MB);
  bf16* vtb  = (bf16*)(w + 32 * MB);    // [B,H,64,S] (kv-permuted cols)
  bf16* atb  = (bf16*)(w + 40 * MB);    // [B,S,DIM]
  float* tc  = (float*)(w + 48 * MB);
  float* ts  = (float*)(w + 48 * MB + 256 * 1024);

  prep_kernel<<<8448, 256, 0, stream>>>(
      x, Wq, Wk, Wv, Wo, (unsigned short*)xb,
      (unsigned short*)wqb, (unsigned short*)wkb, (unsigned short*)wvb,
      (unsigned short*)wob, tc, ts);

  qkv_kernel<<<dim3(32, 24), 256, 0, stream>>>(
      xb, wqb, wkb, wvb, bq, bk, bv, tc, ts,
      (unsigned short*)qbn, (unsigned short*)kbn, (unsigned short*)vtb);

  attn_kernel<<<1024, 256, 0, stream>>>(qbn, kbn, vtb, lsc,
                                        (unsigned short*)atb);

  gemm_bt_kernel<<<dim3(32, 16), 256, 0, stream>>>(atb, wob, bo, (float*)d_out);
}

// Round 19
// 102.232 us; speedup vs baseline: 1.0712x; 1.0592x over previous
//
#include <hip/hip_runtime.h>
#include <hip/hip_bf16.h>
#include <math.h>

typedef __hip_bfloat16 bf16;
typedef __attribute__((ext_vector_type(8))) short short8;
typedef __attribute__((ext_vector_type(4))) float floatx4;

static constexpr int Bn = 2, Sn = 2048, Hn = 16, DHn = 64, DIMn = 1024;
static constexpr int Mn = Bn * Sn;  // 4096 tokens

#if __has_builtin(__builtin_amdgcn_exp2f)
#define EXP2(x) __builtin_amdgcn_exp2f(x)
#else
#define EXP2(x) exp2f(x)
#endif

__device__ __forceinline__ unsigned short bfbits(float f) {
  union { __hip_bfloat16 h; unsigned short u; } cv;
  cv.h = __float2bfloat16(f);
  return cv.u;
}

__device__ __forceinline__ float bf2f(unsigned short u) {
  union { float f; unsigned int u; } cv;
  cv.u = ((unsigned int)u) << 16;
  return cv.f;
}

// truncate-pack two f32 to a bf16-pair dword (lo in low half)
__device__ __forceinline__ unsigned int pack_bf16(float lo, float hi) {
  union { float f; unsigned int u; } a, b;
  a.f = lo; b.f = hi;
  return (b.u & 0xFFFF0000u) | (a.u >> 16);
}

// async global->LDS, 16B per lane. dst is wave-uniform base; HW adds lane*16.
__device__ __forceinline__ void gload_lds16(const void* g, void* l) {
  __builtin_amdgcn_global_load_lds(
      (const __attribute__((address_space(1))) uint32_t*)g,
      (__attribute__((address_space(3))) uint32_t*)l, 16, 0, 0);
}

// counted waits (T4). sched_barrier pins per rule #18.
template <int N>
__device__ __forceinline__ void wait_vm() {
  if constexpr (N == 0) asm volatile("s_waitcnt vmcnt(0)" ::: "memory");
  else if constexpr (N == 2) asm volatile("s_waitcnt vmcnt(2)" ::: "memory");
  else if constexpr (N == 3) asm volatile("s_waitcnt vmcnt(3)" ::: "memory");
  else if constexpr (N == 4) asm volatile("s_waitcnt vmcnt(4)" ::: "memory");
  else asm volatile("s_waitcnt vmcnt(6)" ::: "memory");
  __builtin_amdgcn_sched_barrier(0);
}

// ---------------- fused prep: x->bf16 | 4 weights->bf16 | rope tables ----------------
__global__ void prep_kernel(const float* __restrict__ x,
                            const float* __restrict__ a0, const float* __restrict__ a1,
                            const float* __restrict__ a2, const float* __restrict__ a3,
                            unsigned short* __restrict__ xo,
                            unsigned short* __restrict__ o0, unsigned short* __restrict__ o1,
                            unsigned short* __restrict__ o2, unsigned short* __restrict__ o3,
                            float* __restrict__ tc, float* __restrict__ ts) {
  const int bid = blockIdx.x;
  if (bid < 8192) {
    const float* s;
    unsigned short* d;
    int i;
    if (bid < 4096) {
      s = x; d = xo; i = bid * 256 + threadIdx.x;
    } else {
      int wsel = (bid - 4096) >> 10;
      s = (wsel == 0) ? a0 : (wsel == 1) ? a1 : (wsel == 2) ? a2 : a3;
      d = (wsel == 0) ? o0 : (wsel == 1) ? o1 : (wsel == 2) ? o2 : o3;
      i = ((bid - 4096) & 1023) * 256 + threadIdx.x;
    }
    float4 v = ((const float4*)s)[i];
    ushort4 o;
    o.x = bfbits(v.x); o.y = bfbits(v.y); o.z = bfbits(v.z); o.w = bfbits(v.w);
    ((ushort4*)d)[i] = o;
  } else {
    int t = (bid - 8192) * 256 + threadIdx.x;  // 2048*32 = 65536
    int pos = t >> 5, i = t & 31;
    float f = powf(10000.0f, -(float)i * (1.0f / 32.0f));
    float a = (float)pos * f;
    tc[t] = cosf(a);
    ts[t] = sinf(a);
  }
}

// ---------------- fused QKV GEMM + RoPE + l2norm: 128m x 128n (2 heads) ----------------
// BK=64, 128B LDS rows, XOR-swizzled (zero-conflict). grid (32, 24):
// sel = y>>3, n0 = (y&7)*128 = two heads. A double-buffered (depth-2),
// B single-buffered (staged after barrier-2, consumed next iter).
// LDS = 32KB(A) + 16KB(B) = 48KB -> 3 blocks/CU. 32 MFMA / 20 ds_read per
// K-step, half the barriers per MFMA of the 128x64 version.
__global__ __launch_bounds__(256, 3) void qkv_kernel(
    const bf16* __restrict__ A,
    const bf16* __restrict__ Wq, const bf16* __restrict__ Wk, const bf16* __restrict__ Wv,
    const float* __restrict__ bq, const float* __restrict__ bk, const float* __restrict__ bv,
    const float* __restrict__ tc, const float* __restrict__ ts,
    unsigned short* __restrict__ qo, unsigned short* __restrict__ ko,
    unsigned short* __restrict__ vt) {
  __shared__ bf16 smem[24576];  // sA[2][8192] 32KB | sB[8192] 16KB; ct reuses sA
  bf16* sAp = smem;
  bf16* sBp = smem + 16384;
  const int sel = blockIdx.y >> 3;
  const bf16* Bw = (sel == 0) ? Wq : (sel == 1) ? Wk : Wv;
  const float* bias = (sel == 0) ? bq : (sel == 1) ? bk : bv;
  const int tid = threadIdx.x;
  const int lane = tid & 63, wave = tid >> 6;
  const int fr = lane & 15, fq = lane >> 4;
  const int m0 = blockIdx.x * 128, n0 = (blockIdx.y & 7) * 128;

  floatx4 acc[2][8] = {};  // [mi][ni]; wave rows: wave*32 + mi*16 + ...

  auto stageA = [&](int buf, int k0) {
#pragma unroll
    for (int call = 0; call < 4; ++call) {
      int row = call * 32 + (tid >> 3);
      int sb = ((tid & 7) * 16) ^ ((row & 7) << 4);
      gload_lds16(A + (size_t)(m0 + row) * 1024 + k0 + sb / 2,
                  sAp + buf * 8192 + call * 2048 + wave * 512);
    }
  };
  auto stageB = [&](int k0) {
#pragma unroll
    for (int call = 0; call < 4; ++call) {
      int row = call * 32 + (tid >> 3);
      int sb = ((tid & 7) * 16) ^ ((row & 7) << 4);
      gload_lds16(Bw + (size_t)(n0 + row) * 1024 + k0 + sb / 2,
                  sBp + call * 2048 + wave * 512);
    }
  };

  stageB(0);        // oldest
  stageA(0, 0);
  stageA(1, 64);    // newest 4
  int cur = 0;
  for (int k0 = 0; k0 < 1024; k0 += 64) {
    if (k0 + 64 < 1024) wait_vm<4>(); else wait_vm<0>();
    __builtin_amdgcn_s_barrier();
    __builtin_amdgcn_sched_barrier(0);
    const char* sAc = (const char*)(sAp + cur * 8192);
    const char* sBc = (const char*)sBp;
    short8 af[2][2];
#pragma unroll
    for (int mi = 0; mi < 2; ++mi) {
      int arow = wave * 32 + mi * 16 + fr;
      int asw = (arow & 7) << 4;
#pragma unroll
      for (int kc = 0; kc < 2; ++kc)
        af[mi][kc] = *(const short8*)(sAc + arow * 128 + ((kc * 64 + fq * 16) ^ asw));
    }
#pragma unroll
    for (int nh = 0; nh < 2; ++nh) {  // two ni-halves: caps live B-frag regs
      short8 bfr[4][2];
#pragma unroll
      for (int n4 = 0; n4 < 4; ++n4) {
        int brow = (nh * 4 + n4) * 16 + fr;
        int bsw = (brow & 7) << 4;
#pragma unroll
        for (int kc = 0; kc < 2; ++kc)
          bfr[n4][kc] = *(const short8*)(sBc + brow * 128 + ((kc * 64 + fq * 16) ^ bsw));
      }
#pragma unroll
      for (int mi = 0; mi < 2; ++mi)
#pragma unroll
        for (int n4 = 0; n4 < 4; ++n4)
#pragma unroll
          for (int kc = 0; kc < 2; ++kc)
            acc[mi][nh * 4 + n4] = __builtin_amdgcn_mfma_f32_16x16x32_bf16(
                af[mi][kc], bfr[n4][kc], acc[mi][nh * 4 + n4], 0, 0, 0);
    }
    __builtin_amdgcn_sched_barrier(0);
    __builtin_amdgcn_s_barrier();
    if (k0 + 64 < 1024) stageB(k0 + 64);     // depth-1 (older than A below)
    if (k0 + 128 < 1024) stageA(cur, k0 + 128);  // depth-2 (newest 4)
    cur ^= 1;
  }

  if (sel < 2) {
    // fused bias + RoPE + l2norm epilogue (f32) per head; write [B,H,S,64]
    unsigned short* dst = (sel == 0) ? qo : ko;
    const int h0 = n0 >> 6;
    float bias_d[8];
#pragma unroll
    for (int ni = 0; ni < 8; ++ni) bias_d[ni] = bias[n0 + ni * 16 + fr];
#pragma unroll
    for (int mi = 0; mi < 2; ++mi)
#pragma unroll
      for (int j = 0; j < 4; ++j) {
        int m = m0 + wave * 32 + mi * 16 + fq * 4 + j;
        int b = m >> 11, srow = m & 2047;
#pragma unroll
        for (int hh = 0; hh < 2; ++hh) {
          float y[4], ss = 0.f;
#pragma unroll
          for (int n4 = 0; n4 < 4; ++n4) {
            int ni = hh * 4 + n4;
            float val = acc[mi][ni][j] + bias_d[ni];
            float prt = __shfl_xor(val, 1);
            int d = n4 * 16 + fr;  // dim within head
            int jj = d >> 1;
            float cc = tc[srow * 32 + jj], sn = ts[srow * 32 + jj];
            y[n4] = (d & 1) ? (val * cc + prt * sn) : (val * cc - prt * sn);
            ss += y[n4] * y[n4];
          }
          ss += __shfl_xor(ss, 1);
          ss += __shfl_xor(ss, 2);
          ss += __shfl_xor(ss, 4);
          ss += __shfl_xor(ss, 8);
          float inv = rsqrtf(ss + 1e-6f);
          size_t ob = ((size_t)(b * 16 + h0 + hh) * 2048 + srow) * 64;
#pragma unroll
          for (int n4 = 0; n4 < 4; ++n4)
            dst[ob + n4 * 16 + fr] = bfbits(y[n4] * inv);
        }
      }
  } else {
    // V: transpose through LDS (256B rows), kv-permuted store per 64-group.
    __syncthreads();
    char* ct = (char*)smem;  // [nl 128][ml 128] bf16, 256B rows, ^=(nl&15)<<4 (32KB)
#pragma unroll
    for (int mi = 0; mi < 2; ++mi)
#pragma unroll
      for (int ni = 0; ni < 8; ++ni) {
        int nl = ni * 16 + fr;
        float bi = bias[n0 + nl];
#pragma unroll
        for (int j = 0; j < 4; j += 2) {
          int ml = wave * 32 + mi * 16 + fq * 4 + j;
          unsigned int u = (unsigned int)bfbits(acc[mi][ni][j] + bi) |
                           ((unsigned int)bfbits(acc[mi][ni][j + 1] + bi) << 16);
          *(unsigned int*)(ct + nl * 256 + ((ml * 2) ^ ((nl & 15) << 4))) = u;
        }
      }
    __syncthreads();
    int nl2 = tid >> 1, half = tid & 1;  // 128 rows x 2 threads (one 64-group each)
    int head = (n0 >> 6) + (nl2 >> 6), dd = nl2 & 63;
    int b = m0 >> 11, s0 = m0 & 2047;
    unsigned short* orow =
        vt + (((size_t)b * 16 + head) * 64 + dd) * 2048 + s0 + half * 64;
    int swz = (nl2 & 15) << 4;
    const char* rowp = ct + nl2 * 256;
#pragma unroll
    for (int ch = 0; ch < 4; ++ch) {
      int cb = half * 128 + 32 * (ch >> 1) + 16 * (ch & 1);
      union { long long l[2]; short8 v; } s1, s2;
      s1.l[0] = *(const long long*)(rowp + ((cb) ^ swz));
      s1.l[1] = *(const long long*)(rowp + ((cb + 64) ^ swz));
      s2.l[0] = *(const long long*)(rowp + ((cb + 8) ^ swz));
      s2.l[1] = *(const long long*)(rowp + ((cb + 72) ^ swz));
      *(short8*)(orow + ch * 16) = s1.v;
      *(short8*)(orow + ch * 16 + 8) = s2.v;
    }
  }
}

// ---------------- Wo GEMM: 128m x 64n tiles, BK=64, swizzled, f32 out ----------------
__global__ __launch_bounds__(256, 3) void gemm_bt_kernel(
    const bf16* __restrict__ A, const bf16* __restrict__ Bw,
    const float* __restrict__ bias, float* __restrict__ Cf) {
  __shared__ bf16 smem[24576];  // sA[2][8192] | sB[2][4096]
  bf16* sAp = smem;
  bf16* sBp = smem + 16384;
  const int tid = threadIdx.x;
  const int lane = tid & 63, wave = tid >> 6;
  const int fr = lane & 15, fq = lane >> 4;
  const int m0 = blockIdx.x * 128, n0 = blockIdx.y * 64;

  floatx4 acc[2][4] = {};

  auto stage = [&](int buf, int k0) {
#pragma unroll
    for (int call = 0; call < 4; ++call) {
      int row = call * 32 + (tid >> 3);
      int sb = ((tid & 7) * 16) ^ ((row & 7) << 4);
      gload_lds16(A + (size_t)(m0 + row) * 1024 + k0 + sb / 2,
                  sAp + buf * 8192 + call * 2048 + wave * 512);
    }
#pragma unroll
    for (int call = 0; call < 2; ++call) {
      int row = call * 32 + (tid >> 3);
      int sb = ((tid & 7) * 16) ^ ((row & 7) << 4);
      gload_lds16(Bw + (size_t)(n0 + row) * 1024 + k0 + sb / 2,
                  sBp + buf * 4096 + call * 2048 + wave * 512);
    }
  };

  stage(0, 0);
  stage(1, 64);
  int cur = 0;
  for (int k0 = 0; k0 < 1024; k0 += 64) {
    if (k0 + 64 < 1024) wait_vm<6>(); else wait_vm<0>();
    __builtin_amdgcn_s_barrier();
    __builtin_amdgcn_sched_barrier(0);
    const char* sAc = (const char*)(sAp + cur * 8192);
    const char* sBc = (const char*)(sBp + cur * 4096);
    short8 af[2][2], bfr[4][2];
#pragma unroll
    for (int mi = 0; mi < 2; ++mi) {
      int arow = wave * 32 + mi * 16 + fr;
      int asw = (arow & 7) << 4;
#pragma unroll
      for (int kc = 0; kc < 2; ++kc)
        af[mi][kc] = *(const short8*)(sAc + arow * 128 + ((kc * 64 + fq * 16) ^ asw));
    }
#pragma unroll
    for (int ni = 0; ni < 4; ++ni) {
      int brow = ni * 16 + fr;
      int bsw = (brow & 7) << 4;
#pragma unroll
      for (int kc = 0; kc < 2; ++kc)
        bfr[ni][kc] = *(const short8*)(sBc + brow * 128 + ((kc * 64 + fq * 16) ^ bsw));
    }
#pragma unroll
    for (int mi = 0; mi < 2; ++mi)
#pragma unroll
      for (int ni = 0; ni < 4; ++ni)
#pragma unroll
        for (int kc = 0; kc < 2; ++kc)
          acc[mi][ni] = __builtin_amdgcn_mfma_f32_16x16x32_bf16(af[mi][kc], bfr[ni][kc],
                                                               acc[mi][ni], 0, 0, 0);
    __builtin_amdgcn_sched_barrier(0);
    __builtin_amdgcn_s_barrier();
    if (k0 + 128 < 1024) stage(cur, k0 + 128);
    cur ^= 1;
  }

#pragma unroll
  for (int ni = 0; ni < 4; ++ni) {
    int n = n0 + ni * 16 + fr;
    float bi = bias[n];
#pragma unroll
    for (int mi = 0; mi < 2; ++mi)
#pragma unroll
      for (int j = 0; j < 4; ++j) {
        int m = m0 + wave * 32 + mi * 16 + fq * 4 + j;
        Cf[(size_t)m * 1024 + n] = acc[mi][ni][j] + bi;
      }
  }
}

// ---------------- causal flash attention (r11 structure + XCD-confined heads) ----------------
// grid 1024 (1D). bid -> (bh, xq): bh = (bid&7)*4 + ((bid>>3)&3) groups all 32
// blocks of a head onto one XCD (bid%8 = XCD round-robin), confining each
// head's K/V (512KB) to one 4MB XCD-L2 (4 heads/XCD = 2MB). xq piecewise map
// (j8 / 31-j8 / 8+j8 / 23-j8 by j>>3) is bijective over 0..31 and keeps the
// per-CU iteration sums constant (co-resident blocks take one value from each
// branch -> sum 62). Swapped-QK in-register softmax; kv-permuted V; 32KB LDS.
__global__ __launch_bounds__(256, 5) void attn_kernel(
    const bf16* __restrict__ qb, const bf16* __restrict__ kb, const bf16* __restrict__ vt,
    const float* __restrict__ ls, unsigned short* __restrict__ out) {
  __shared__ bf16 sK[2][64 * 64];   // [kv][d], 128B rows, swz (row&7)<<4
  __shared__ bf16 sV[2][64 * 64];   // [d][pos], 128B rows, swz (row&7)<<4
  const int bid = blockIdx.x;
  const int bh = (bid & 7) * 4 + ((bid >> 3) & 3);
  const int j = bid >> 5;             // 0..31
  const int j8 = j & 7, sl = j >> 3;  // branch 0..3
  const int xq = (sl == 0) ? j8 : (sl == 1) ? (31 - j8) : (sl == 2) ? (8 + j8) : (23 - j8);
  const int q0A = xq * 32, q0B = (63 - xq) * 32;
  const int tid = threadIdx.x;
  const int lane = tid & 63, wave = tid >> 6;
  const int fr = lane & 15, fq = lane >> 4;
  const int myq0 = ((((wave >> 1) ^ bid) & 1)) ? q0B : q0A;  // letter flip
  const int base = myq0 + (wave & 1) * 16;
  float scl2 = __expf(ls[0]) * 0.125f * 1.44269504f;

  const size_t qrow = (size_t)bh * 2048 + base + fr;
  short8 qf0 = *(const short8*)(qb + qrow * 64 + fq * 8);
  short8 qf1 = *(const short8*)(qb + qrow * 64 + 32 + fq * 8);
  asm volatile("" : "+v"(qf0), "+v"(qf1), "+v"(scl2));
  __builtin_amdgcn_sched_barrier(0);

  const bf16* kgb = kb + (size_t)bh * 2048 * 64;
  const bf16* vgb = vt + (size_t)bh * 64 * 2048;

  auto stage = [&](int buf, int t0) {
#pragma unroll
    for (int call = 0; call < 2; ++call) {
      int row = call * 32 + (tid >> 3);
      int sb = ((tid & 7) * 16) ^ ((row & 7) << 4);
      gload_lds16(kgb + (size_t)(t0 + row) * 64 + sb / 2,
                  &sK[buf][call * 2048 + wave * 512]);
    }
#pragma unroll
    for (int call = 0; call < 2; ++call) {
      int row = call * 32 + (tid >> 3);
      int sb = ((tid & 7) * 16) ^ ((row & 7) << 4);
      gload_lds16(vgb + (size_t)row * 2048 + t0 + sb / 2,
                  &sV[buf][call * 2048 + wave * 512]);
    }
  };

  floatx4 oacc[4] = {};
  float m_l = -INFINITY, l_l = 0.f;
  const int qrow_l = base + fr;
  const int rowq = base + fq * 4;
  const int sw = (fr & 7) << 4;

  const int tEnd = q0B + 32;
  stage(0, 0);
  stage(1, 64);
  int cur = 0;
  for (int t0 = 0; t0 < tEnd; t0 += 64) {
    if (t0 + 64 < tEnd) wait_vm<4>(); else wait_vm<0>();
    __builtin_amdgcn_s_barrier();
    __builtin_amdgcn_sched_barrier(0);
    if (t0 < myq0 + 32) {
      const char* sKc = (const char*)sK[cur];
      const char* sVc = (const char*)sV[cur];
      floatx4 sacc[4] = {};
      __builtin_amdgcn_s_setprio(1);
#pragma unroll
      for (int c = 0; c < 4; ++c) {
        int rb = (c * 16 + fr) * 128;
        short8 kf0 = *(const short8*)(sKc + rb + ((fq * 16) ^ sw));
        short8 kf1 = *(const short8*)(sKc + rb + ((64 + fq * 16) ^ sw));
        // SWAPPED: A=K (rows=kv), B=Q (rows=q) -> C[kv][q], col=fr=q
        sacc[c] = __builtin_amdgcn_mfma_f32_16x16x32_bf16(kf0, qf0, sacc[c], 0, 0, 0);
        sacc[c] = __builtin_amdgcn_mfma_f32_16x16x32_bf16(kf1, qf1, sacc[c], 0, 0, 0);
      }
      __builtin_amdgcn_s_setprio(0);
      if (t0 + 63 > base) {  // causal mask: kv = t0+16c+4fq+r vs q = base+fr
#pragma unroll
        for (int c = 0; c < 4; ++c)
#pragma unroll
          for (int r = 0; r < 4; ++r)
            if ((t0 + c * 16 + fq * 4 + r) > qrow_l) sacc[c][r] = -1e30f;
      }
      float pm0 = fmaxf(fmaxf(sacc[0][0], sacc[0][1]), fmaxf(sacc[0][2], sacc[0][3]));
      float pm1 = fmaxf(fmaxf(sacc[1][0], sacc[1][1]), fmaxf(sacc[1][2], sacc[1][3]));
      float pm2 = fmaxf(fmaxf(sacc[2][0], sacc[2][1]), fmaxf(sacc[2][2], sacc[2][3]));
      float pm3 = fmaxf(fmaxf(sacc[3][0], sacc[3][1]), fmaxf(sacc[3][2], sacc[3][3]));
      float pm = fmaxf(fmaxf(pm0, pm1), fmaxf(pm2, pm3));
      if (!__all(pm * scl2 - m_l <= 11.5f)) {
        float pmr = fmaxf(pm, __shfl_xor(pm, 16));
        pmr = fmaxf(pmr, __shfl_xor(pmr, 32));
        float mnew = fmaxf(m_l, pmr * scl2);
        float rs = EXP2(m_l - mnew);
        m_l = mnew;
        l_l *= rs;
        float rsr[4];
#pragma unroll
        for (int r = 0; r < 4; ++r) rsr[r] = __shfl(rs, rowq - base + r);
#pragma unroll
        for (int d = 0; d < 4; ++d)
#pragma unroll
          for (int r = 0; r < 4; ++r) oacc[d][r] *= rsr[r];
      }
      float p[4][4];
      float ssum = 0.f;
#pragma unroll
      for (int c = 0; c < 4; ++c)
#pragma unroll
        for (int r = 0; r < 4; ++r) {
          p[c][r] = EXP2(sacc[c][r] * scl2 - m_l);
          ssum += p[c][r];
        }
      ssum += __shfl_xor(ssum, 16);
      ssum += __shfl_xor(ssum, 32);
      l_l += ssum;
      short8 pf[2];
#pragma unroll
      for (int kc = 0; kc < 2; ++kc) {
        union { unsigned int w[4]; short8 v; } pk;
        pk.w[0] = pack_bf16(p[kc][0], p[kc][1]);
        pk.w[1] = pack_bf16(p[kc][2], p[kc][3]);
        pk.w[2] = pack_bf16(p[kc + 2][0], p[kc + 2][1]);
        pk.w[3] = pack_bf16(p[kc + 2][2], p[kc + 2][3]);
        pf[kc] = pk.v;
      }
      __builtin_amdgcn_s_setprio(1);
#pragma unroll
      for (int d = 0; d < 4; ++d) {
        int rbv = (d * 16 + fr) * 128;
#pragma unroll
        for (int kc = 0; kc < 2; ++kc) {
          short8 vf = *(const short8*)(sVc + rbv + ((kc * 64 + fq * 16) ^ sw));
          oacc[d] = __builtin_amdgcn_mfma_f32_16x16x32_bf16(pf[kc], vf, oacc[d], 0, 0, 0);
        }
      }
      __builtin_amdgcn_s_setprio(0);
    }
    __builtin_amdgcn_sched_barrier(0);
    __builtin_amdgcn_s_barrier();
    if (t0 + 128 < tEnd) stage(cur, t0 + 128);
    cur ^= 1;
  }
  const int b = bh >> 4, h = bh & 15;
  float il[4];
#pragma unroll
  for (int r = 0; r < 4; ++r) il[r] = 1.0f / __shfl(l_l, rowq - base + r);
#pragma unroll
  for (int r = 0; r < 4; ++r)
#pragma unroll
    for (int d = 0; d < 4; ++d) {
      size_t o = ((size_t)b * 2048 + rowq + r) * 1024 + h * 64 + d * 16 + fr;
      out[o] = bfbits(oacc[d][r] * il[r]);
    }
}

extern "C" void kernel_launch(void* const* d_in, const int* in_sizes, int n_in,
                              void* d_out, int out_size, void* d_ws, size_t ws_size,
                              hipStream_t stream) {
  (void)in_sizes; (void)n_in; (void)out_size; (void)ws_size;
  const float* x  = (const float*)d_in[0];
  const float* Wq = (const float*)d_in[1];
  const float* bq = (const float*)d_in[2];
  const float* Wk = (const float*)d_in[3];
  const float* bk = (const float*)d_in[4];
  const float* Wv = (const float*)d_in[5];
  const float* bv = (const float*)d_in[6];
  const float* Wo = (const float*)d_in[7];
  const float* bo = (const float*)d_in[8];
  const float* lsc = (const float*)d_in[9];

  uint8_t* w = (uint8_t*)d_ws;
  const size_t MB = 1ull << 20;
  bf16* xb   = (bf16*)(w + 0);          // 8 MB
  bf16* wqb  = (bf16*)(w + 8 * MB);
  bf16* wkb  = (bf16*)(w + 10 * MB);
  bf16* wvb  = (bf16*)(w + 12 * MB);
  bf16* wob  = (bf16*)(w + 14 * MB);
  bf16* qbn  = (bf16*)(w + 16 * MB);    // [B,H,S,64]
  bf16* kbn  = (bf16*)(w + 24 * MB);
  bf16* vtb  = (bf16*)(w + 32 * MB);    // [B,H,64,S] (kv-permuted cols)
  bf16* atb  = (bf16*)(w + 40 * MB);    // [B,S,DIM]
  float* tc  = (float*)(w + 48 * MB);
  float* ts  = (float*)(w + 48 * MB + 256 * 1024);

  prep_kernel<<<8448, 256, 0, stream>>>(
      x, Wq, Wk, Wv, Wo, (unsigned short*)xb,
      (unsigned short*)wqb, (unsigned short*)wkb, (unsigned short*)wvb,
      (unsigned short*)wob, tc, ts);

  qkv_kernel<<<dim3(32, 24), 256, 0, stream>>>(
      xb, wqb, wkb, wvb, bq, bk, bv, tc, ts,
      (unsigned short*)qbn, (unsigned short*)kbn, (unsigned short*)vtb);

  attn_kernel<<<1024, 256, 0, stream>>>(qbn, kbn, vtb, lsc,
                                        (unsigned short*)atb);

  gemm_bt_kernel<<<dim3(32, 16), 256, 0, stream>>>(atb, wob, bo, (float*)d_out);
}